// Round 4
// baseline (200.277 us; speedup 1.0000x reference)
//
#include <hip/hip_runtime.h>
#include <hip/hip_bf16.h>
#include <hip/hip_fp16.h>
#include <math.h>

#define N_NODES   100000
#define N_EDGES   1600000
#define D_FEAT    128
#define N_CLASSES 64

#define BKT_SHIFT 7                     // 128 nodes per bucket
#define BKT_NODES 128
#define NB        782                   // ceil(100000/128)
#define CAP       2560                  // per-bucket capacity (avg 2048)
#define CHUNK     4096                  // edges per bin block (halved: occupancy)
#define NBLK_A    ((N_EDGES + CHUNK - 1) / CHUNK)   // 391
#define NBLK_G    ((N_NODES + 63) / 64)             // 1563
#define NBLK_AGG  6250                  // 25000 nodes per quarter, 4 nodes/block

// ws layout (max extent 21,212,160 B — well under proven 34 MB):
//   meta   @ 0          (400,000 B)  start|(indeg<<21)
//   bcnt   @ 400,384    (3,128 B)
//   binned @ 404,480    (8,007,680 B)
//   zp     @ 8,412,160  (12,800,000 B, fp16)
#define OFF_BCNT   400384
#define OFF_BINNED 404480
#define OFF_ZP     8412160

typedef __attribute__((ext_vector_type(8))) short bf16x8;
typedef __attribute__((ext_vector_type(4))) float f32x4;
typedef __attribute__((ext_vector_type(4))) unsigned int u32x4;

static __device__ inline unsigned f2bf1(float f) {
    unsigned u = __float_as_uint(f);
    return (u + 0x7FFF + ((u >> 16) & 1)) >> 16;     // RNE
}
static __device__ inline unsigned pack2(float a, float b) {
    return f2bf1(a) | (f2bf1(b) << 16);
}
static __device__ inline float2 h2f2(unsigned u) {
    __half2 h = *(__half2*)&u;
    return __half22float2(h);
}

// ---------------------------------------------------------------------------
// K1: bin edges into NB coarse buckets (contiguous per-block runs).
//     CHUNK=4096 -> 391 blocks: ~2 blocks/CU resident (was 196 = half the
//     CUs idle), per-pass latency chains halved.
// ---------------------------------------------------------------------------
__global__ __launch_bounds__(1024) void bin_kernel(const int* __restrict__ src,
                                                   const int* __restrict__ dst,
                                                   int* __restrict__ bcnt,
                                                   int* __restrict__ binned) {
    __shared__ int hist[NB];
    __shared__ int rbase[NB];
    __shared__ int dbuf[CHUNK];                // 16 KB
    const int tid = threadIdx.x;
    const int e0 = blockIdx.x * CHUNK;
    const int e1 = min(e0 + CHUNK, N_EDGES);
    const int n  = e1 - e0;

    for (int i = tid; i < NB; i += 1024) hist[i] = 0;
    __syncthreads();

    for (int i = tid; i < n; i += 1024) {
        int d = dst[e0 + i];
        dbuf[i] = d;
        atomicAdd(&hist[d >> BKT_SHIFT], 1);
    }
    __syncthreads();

    for (int i = tid; i < NB; i += 1024) {
        int h = hist[i];
        if (h) rbase[i] = atomicAdd(&bcnt[i], h);
        hist[i] = 0;                           // reuse as within-run cursor
    }
    __syncthreads();

    for (int i = tid; i < n; i += 1024) {
        int d = dbuf[i];
        int s = src[e0 + i];
        int bkt = d >> BKT_SHIFT;
        int pos = atomicAdd(&hist[bkt], 1);
        int off = rbase[bkt] + pos;
        if (off < CAP)                         // memory guard
            binned[bkt * CAP + off] = (s << BKT_SHIFT) | (d & (BKT_NODES - 1));
    }
}

// ---------------------------------------------------------------------------
// K2: per-bucket in-place sort-by-node + degree metadata.
//     Scatter lands in LDS sorted[]; global write-back is coalesced int4.
// ---------------------------------------------------------------------------
__global__ __launch_bounds__(1024) void sortdeg_kernel(const int* __restrict__ bcnt,
                                                       int* __restrict__ binned,
                                                       int* __restrict__ meta) {
    __shared__ int buf[CAP];
    __shared__ int sorted[CAP];
    __shared__ int hcnt[BKT_NODES];
    __shared__ int cur[BKT_NODES];
    __shared__ int rowstart[BKT_NODES + 1];

    const int tid  = threadIdx.x;
    const int lane = tid & 63;
    const int wid  = tid >> 6;

    if (tid < BKT_NODES) { hcnt[tid] = 0; cur[tid] = 0; }
    __syncthreads();

    const int n    = min(bcnt[blockIdx.x], CAP);
    const int base = blockIdx.x * CAP;

    for (int i = tid; i < n; i += 1024) {
        int v = binned[base + i];
        buf[i] = v;
        atomicAdd(&hcnt[v & (BKT_NODES - 1)], 1);
    }
    __syncthreads();

    if (wid == 0) {
        int v0 = hcnt[lane];
        int v1 = hcnt[64 + lane];
        int s0 = v0;
#pragma unroll
        for (int off = 1; off < 64; off <<= 1) {
            int t = __shfl_up(s0, off, 64);
            if (lane >= off) s0 += t;
        }
        int tot0 = __shfl(s0, 63, 64);
        int s1 = v1;
#pragma unroll
        for (int off = 1; off < 64; off <<= 1) {
            int t = __shfl_up(s1, off, 64);
            if (lane >= off) s1 += t;
        }
        s1 += tot0;
        if (lane == 0) rowstart[0] = 0;
        rowstart[1 + lane]  = s0;
        rowstart[65 + lane] = s1;
    }
    __syncthreads();

    for (int i = tid; i < n; i += 1024) {
        int v  = buf[i];
        int nd = v & (BKT_NODES - 1);
        int p  = atomicAdd(&cur[nd], 1);
        sorted[rowstart[nd] + p] = v >> BKT_SHIFT;   // scattered -> LDS (fast)
    }
    __syncthreads();

    // coalesced write-back (16B where possible)
    const int n4 = n & ~3;
    for (int i = tid * 4; i < n4; i += 4096)
        *(int4*)&binned[base + i] = *(const int4*)&sorted[i];
    for (int i = n4 + tid; i < n; i += 1024)
        binned[base + i] = sorted[i];

    if (tid < BKT_NODES) {
        int node = blockIdx.x * BKT_NODES + tid;
        if (node < N_NODES) {
            int st = base + rowstart[tid];
            int dg = min(hcnt[tid], 2047);
            meta[node] = st | (dg << 21);
        }
    }
}

// ---------------------------------------------------------------------------
// K3: zp[i][c] = rsqrt(indeg[i]+1) * (x @ W^T)[i][c]  via bf16 MFMA, fp16 out.
// ---------------------------------------------------------------------------
__global__ __launch_bounds__(256) void gemm_kernel(const float* __restrict__ x,
                                                   const float* __restrict__ W,
                                                   const int* __restrict__ meta,
                                                   __half* __restrict__ zp) {
    __shared__ short Xb[64 * 136];
    __shared__ short Wb[64 * 136];
    const int tid  = threadIdx.x;
    const int row0 = blockIdx.x * 64;

    const float4* __restrict__ W4 = (const float4*)W;
    for (int idx = tid; idx < 64 * 32; idx += 256) {
        int nn = idx >> 5, k4 = idx & 31;
        float4 v = W4[idx];
        uint2 p;
        p.x = pack2(v.x, v.y);
        p.y = pack2(v.z, v.w);
        *(uint2*)&Wb[nn * 136 + k4 * 4] = p;
    }
    const float4* __restrict__ x4 = (const float4*)x;
    for (int idx = tid; idx < 64 * 32; idx += 256) {
        int r = idx >> 5, k4 = idx & 31;
        int gr = min(row0 + r, N_NODES - 1);
        float4 v = x4[gr * 32 + k4];
        uint2 p;
        p.x = pack2(v.x, v.y);
        p.y = pack2(v.z, v.w);
        *(uint2*)&Xb[r * 136 + k4 * 4] = p;
    }
    __syncthreads();

    const int lane = tid & 63;
    const int wv   = tid >> 6;
    const int m    = lane & 15;
    const int half = lane >> 4;

    bf16x8 bfr[4][4];
#pragma unroll
    for (int t = 0; t < 4; t++)
#pragma unroll
        for (int j = 0; j < 4; j++)
            bfr[t][j] = *(bf16x8*)&Wb[(j * 16 + m) * 136 + t * 32 + half * 8];

    f32x4 acc[4];
#pragma unroll
    for (int j = 0; j < 4; j++) acc[j] = (f32x4){0.f, 0.f, 0.f, 0.f};

#pragma unroll
    for (int t = 0; t < 4; t++) {
        bf16x8 a = *(bf16x8*)&Xb[(wv * 16 + m) * 136 + t * 32 + half * 8];
#pragma unroll
        for (int j = 0; j < 4; j++)
            acc[j] = __builtin_amdgcn_mfma_f32_16x16x32_bf16(a, bfr[t][j], acc[j], 0, 0, 0);
    }

#pragma unroll
    for (int r = 0; r < 4; r++) {
        const int row = row0 + wv * 16 + half * 4 + r;
        if (row < N_NODES) {
            const int dg = ((unsigned)meta[row]) >> 21;
            const float dinv = rsqrtf((float)(dg + 1));
#pragma unroll
            for (int j = 0; j < 4; j++)
                zp[row * N_CLASSES + j * 16 + m] = __float2half(acc[j][r] * dinv);
        }
    }
}

// ---------------------------------------------------------------------------
// K4: gather-accumulate + fused epilogue. One wave per node. (round-0 form,
//     proven 53.8 us.) Launched as 4 quarter-grids so the OTHER kernels
//     surface in the profiler's top-5 — diagnostic for next round.
// ---------------------------------------------------------------------------
__global__ __launch_bounds__(256) void agg_kernel(const int* __restrict__ meta,
                                                  const int* __restrict__ binned,
                                                  const __half* __restrict__ zp,
                                                  const float* __restrict__ b,
                                                  float* __restrict__ out,
                                                  int nbase) {
    const int node = nbase + blockIdx.x * 4 + (threadIdx.x >> 6);
    const int lane = threadIdx.x & 63;
    const int sub  = lane >> 3;                 // edge slot 0..7
    const int o8   = (lane & 7) * 8;            // class octet start

    const unsigned mv = (unsigned)meta[node];
    const int start = mv & 0x1FFFFF;
    const int cnt   = mv >> 21;

    float a[8] = {0.f, 0.f, 0.f, 0.f, 0.f, 0.f, 0.f, 0.f};
    for (int base = 0; base < cnt; base += 64) {
        const int bn = min(cnt - base, 64);
        // one load -> 64 indices for this batch
        const int sidx = binned[start + base + min(lane, bn - 1)];
        const int jm = (bn + 7) >> 3;
        for (int j = 0; j < jm; j++) {
            const int eid = j * 8 + sub;
            const int row = __shfl(sidx, min(eid, bn - 1), 64);
            const u32x4 g = *(const u32x4*)&zp[row * N_CLASSES + o8];
            if (eid < bn) {
#pragma unroll
                for (int k = 0; k < 4; k++) {
                    float2 f = h2f2(g[k]);
                    a[2 * k]     += f.x;
                    a[2 * k + 1] += f.y;
                }
            }
        }
    }
    // combine the 8 edge slots (xor 8,16,32): each octet-lane ends with full sums
#pragma unroll
    for (int mask = 8; mask <= 32; mask <<= 1)
#pragma unroll
        for (int k = 0; k < 8; k++)
            a[k] += __shfl_xor(a[k], mask, 64);

    // self-loop
    const u32x4 sg = *(const u32x4*)&zp[node * N_CLASSES + o8];
#pragma unroll
    for (int k = 0; k < 4; k++) {
        float2 f = h2f2(sg[k]);
        a[2 * k]     += f.x;
        a[2 * k + 1] += f.y;
    }

    const float dinv = rsqrtf((float)(cnt + 1));
    float v[8];
#pragma unroll
    for (int k = 0; k < 8; k++) v[k] = a[k] * dinv + b[o8 + k];

    // max/sum over 8 local + the 8 octet lanes (masks 1,2,4 stay in-octet)
    float m = v[0];
#pragma unroll
    for (int k = 1; k < 8; k++) m = fmaxf(m, v[k]);
#pragma unroll
    for (int mask = 1; mask <= 4; mask <<= 1)
        m = fmaxf(m, __shfl_xor(m, mask, 64));
    float l = 0.f;
#pragma unroll
    for (int k = 0; k < 8; k++) l += __expf(v[k] - m);
#pragma unroll
    for (int mask = 1; mask <= 4; mask <<= 1)
        l += __shfl_xor(l, mask, 64);
    const float lg = m + __logf(l);

    if (sub == 0) {
        float4 o0, o1;
        o0.x = v[0] - lg; o0.y = v[1] - lg; o0.z = v[2] - lg; o0.w = v[3] - lg;
        o1.x = v[4] - lg; o1.y = v[5] - lg; o1.z = v[6] - lg; o1.w = v[7] - lg;
        *(float4*)&out[node * N_CLASSES + o8]     = o0;
        *(float4*)&out[node * N_CLASSES + o8 + 4] = o1;
    }
}

// ---------------------------------------------------------------------------
// Launch
// ---------------------------------------------------------------------------
extern "C" void kernel_launch(void* const* d_in, const int* in_sizes, int n_in,
                              void* d_out, int out_size, void* d_ws, size_t ws_size,
                              hipStream_t stream) {
    const float* x    = (const float*)d_in[0];
    const int*   edge = (const int*)d_in[1];   // [2,E]: src then dst
    const float* W    = (const float*)d_in[2];
    const float* b    = (const float*)d_in[3];
    float* out = (float*)d_out;

    char* ws = (char*)d_ws;
    int*    meta   = (int*)(ws);
    int*    bcnt   = (int*)(ws + OFF_BCNT);
    int*    binned = (int*)(ws + OFF_BINNED);
    __half* zp     = (__half*)(ws + OFF_ZP);

    const int* srcv = edge;
    const int* dstv = edge + N_EDGES;

    hipMemsetAsync(bcnt, 0, NB * sizeof(int), stream);
    bin_kernel<<<NBLK_A, 1024, 0, stream>>>(srcv, dstv, bcnt, binned);
    sortdeg_kernel<<<NB, 1024, 0, stream>>>(bcnt, binned, meta);
    gemm_kernel<<<NBLK_G, 256, 0, stream>>>(x, W, meta, zp);
    for (int q = 0; q < 4; q++)
        agg_kernel<<<NBLK_AGG, 256, 0, stream>>>(meta, binned, zp, b, out, q * 25000);
}

// Round 5
// 177.522 us; speedup vs baseline: 1.1282x; 1.1282x over previous
//
#include <hip/hip_runtime.h>
#include <hip/hip_bf16.h>
#include <hip/hip_fp16.h>
#include <math.h>

#define N_NODES   100000
#define N_EDGES   1600000
#define D_FEAT    128
#define N_CLASSES 64

#define BKT_SHIFT 7                     // 128 nodes per bucket
#define BKT_NODES 128
#define NB        782                   // ceil(100000/128)
#define CAP       2560                  // per-bucket capacity (avg 2048)
#define CHUNK     8192                  // edges per bin block (round-0 proven)
#define NBLK_A    ((N_EDGES + CHUNK - 1) / CHUNK)   // 196
#define NBLK_G    ((N_NODES + 63) / 64)             // 1563

// ws layout (max extent 21,212,160 B):
//   meta   @ 0          (400,000 B)  start|(indeg<<21)
//   bcnt   @ 400,384    (3,128 B)
//   binned @ 404,480    (8,007,680 B)
//   zp     @ 8,412,160  (12,800,000 B, fp16)
#define OFF_BCNT   400384
#define OFF_BINNED 404480
#define OFF_ZP     8412160

typedef __attribute__((ext_vector_type(8))) short bf16x8;
typedef __attribute__((ext_vector_type(4))) float f32x4;
typedef __attribute__((ext_vector_type(4))) unsigned int u32x4;

static __device__ inline unsigned f2bf1(float f) {
    unsigned u = __float_as_uint(f);
    return (u + 0x7FFF + ((u >> 16) & 1)) >> 16;     // RNE
}
static __device__ inline unsigned pack2(float a, float b) {
    return f2bf1(a) | (f2bf1(b) << 16);
}
static __device__ inline float2 h2f2(unsigned u) {
    __half2 h = *(__half2*)&u;
    return __half22float2(h);
}

// ---------------------------------------------------------------------------
// K1: bin edges into NB coarse buckets (contiguous per-block runs).
//     (round-0 form, proven)
// ---------------------------------------------------------------------------
__global__ __launch_bounds__(1024) void bin_kernel(const int* __restrict__ src,
                                                   const int* __restrict__ dst,
                                                   int* __restrict__ bcnt,
                                                   int* __restrict__ binned) {
    __shared__ int hist[NB];
    __shared__ int rbase[NB];
    __shared__ int dbuf[CHUNK];                // 32 KB
    const int tid = threadIdx.x;
    const int e0 = blockIdx.x * CHUNK;
    const int e1 = min(e0 + CHUNK, N_EDGES);
    const int n  = e1 - e0;

    for (int i = tid; i < NB; i += 1024) hist[i] = 0;
    __syncthreads();

    for (int i = tid; i < n; i += 1024) {
        int d = dst[e0 + i];
        dbuf[i] = d;
        atomicAdd(&hist[d >> BKT_SHIFT], 1);
    }
    __syncthreads();

    for (int i = tid; i < NB; i += 1024) {
        int h = hist[i];
        if (h) rbase[i] = atomicAdd(&bcnt[i], h);
        hist[i] = 0;                           // reuse as within-run cursor
    }
    __syncthreads();

    for (int i = tid; i < n; i += 1024) {
        int d = dbuf[i];
        int s = src[e0 + i];
        int bkt = d >> BKT_SHIFT;
        int pos = atomicAdd(&hist[bkt], 1);
        int off = rbase[bkt] + pos;
        if (off < CAP)                         // memory guard
            binned[bkt * CAP + off] = (s << BKT_SHIFT) | (d & (BKT_NODES - 1));
    }
}

// ---------------------------------------------------------------------------
// K2: per-bucket in-place sort-by-node + degree metadata. (round-0 form)
// ---------------------------------------------------------------------------
__global__ __launch_bounds__(1024) void sortdeg_kernel(const int* __restrict__ bcnt,
                                                       int* __restrict__ binned,
                                                       int* __restrict__ meta) {
    __shared__ int buf[CAP];
    __shared__ int hcnt[BKT_NODES];
    __shared__ int cur[BKT_NODES];
    __shared__ int rowstart[BKT_NODES + 1];

    const int tid  = threadIdx.x;
    const int lane = tid & 63;
    const int wid  = tid >> 6;

    if (tid < BKT_NODES) { hcnt[tid] = 0; cur[tid] = 0; }
    __syncthreads();

    const int n    = min(bcnt[blockIdx.x], CAP);
    const int base = blockIdx.x * CAP;

    for (int i = tid; i < n; i += 1024) {
        int v = binned[base + i];
        buf[i] = v;
        atomicAdd(&hcnt[v & (BKT_NODES - 1)], 1);
    }
    __syncthreads();

    if (wid == 0) {
        int v0 = hcnt[lane];
        int v1 = hcnt[64 + lane];
        int s0 = v0;
#pragma unroll
        for (int off = 1; off < 64; off <<= 1) {
            int t = __shfl_up(s0, off, 64);
            if (lane >= off) s0 += t;
        }
        int tot0 = __shfl(s0, 63, 64);
        int s1 = v1;
#pragma unroll
        for (int off = 1; off < 64; off <<= 1) {
            int t = __shfl_up(s1, off, 64);
            if (lane >= off) s1 += t;
        }
        s1 += tot0;
        if (lane == 0) rowstart[0] = 0;
        rowstart[1 + lane]  = s0;
        rowstart[65 + lane] = s1;
    }
    __syncthreads();

    for (int i = tid; i < n; i += 1024) {
        int v  = buf[i];
        int nd = v & (BKT_NODES - 1);
        int p  = atomicAdd(&cur[nd], 1);
        binned[base + rowstart[nd] + p] = v >> BKT_SHIFT;
    }

    if (tid < BKT_NODES) {
        int node = blockIdx.x * BKT_NODES + tid;
        if (node < N_NODES) {
            int st = base + rowstart[tid];
            int dg = min(hcnt[tid], 2047);
            meta[node] = st | (dg << 21);
        }
    }
}

// ---------------------------------------------------------------------------
// K3: zp[i][c] = rsqrt(indeg[i]+1) * (x @ W^T)[i][c]  via bf16 MFMA, fp16 out.
// ---------------------------------------------------------------------------
__global__ __launch_bounds__(256) void gemm_kernel(const float* __restrict__ x,
                                                   const float* __restrict__ W,
                                                   const int* __restrict__ meta,
                                                   __half* __restrict__ zp) {
    __shared__ short Xb[64 * 136];
    __shared__ short Wb[64 * 136];
    const int tid  = threadIdx.x;
    const int row0 = blockIdx.x * 64;

    const float4* __restrict__ W4 = (const float4*)W;
    for (int idx = tid; idx < 64 * 32; idx += 256) {
        int nn = idx >> 5, k4 = idx & 31;
        float4 v = W4[idx];
        uint2 p;
        p.x = pack2(v.x, v.y);
        p.y = pack2(v.z, v.w);
        *(uint2*)&Wb[nn * 136 + k4 * 4] = p;
    }
    const float4* __restrict__ x4 = (const float4*)x;
    for (int idx = tid; idx < 64 * 32; idx += 256) {
        int r = idx >> 5, k4 = idx & 31;
        int gr = min(row0 + r, N_NODES - 1);
        float4 v = x4[gr * 32 + k4];
        uint2 p;
        p.x = pack2(v.x, v.y);
        p.y = pack2(v.z, v.w);
        *(uint2*)&Xb[r * 136 + k4 * 4] = p;
    }
    __syncthreads();

    const int lane = tid & 63;
    const int wv   = tid >> 6;
    const int m    = lane & 15;
    const int half = lane >> 4;

    bf16x8 bfr[4][4];
#pragma unroll
    for (int t = 0; t < 4; t++)
#pragma unroll
        for (int j = 0; j < 4; j++)
            bfr[t][j] = *(bf16x8*)&Wb[(j * 16 + m) * 136 + t * 32 + half * 8];

    f32x4 acc[4];
#pragma unroll
    for (int j = 0; j < 4; j++) acc[j] = (f32x4){0.f, 0.f, 0.f, 0.f};

#pragma unroll
    for (int t = 0; t < 4; t++) {
        bf16x8 a = *(bf16x8*)&Xb[(wv * 16 + m) * 136 + t * 32 + half * 8];
#pragma unroll
        for (int j = 0; j < 4; j++)
            acc[j] = __builtin_amdgcn_mfma_f32_16x16x32_bf16(a, bfr[t][j], acc[j], 0, 0, 0);
    }

#pragma unroll
    for (int r = 0; r < 4; r++) {
        const int row = row0 + wv * 16 + half * 4 + r;
        if (row < N_NODES) {
            const int dg = ((unsigned)meta[row]) >> 21;
            const float dinv = rsqrtf((float)(dg + 1));
#pragma unroll
            for (int j = 0; j < 4; j++)
                zp[row * N_CLASSES + j * 16 + m] = __float2half(acc[j][r] * dinv);
        }
    }
}

// ---------------------------------------------------------------------------
// K4: gather-accumulate + fused epilogue. TWO nodes per wave:
//     lanes 0-31 = node A, lanes 32-63 = node B; within a half: 4 edge slots
//     x 8 class octets. Edge-loop throughput identical to round-0 (8 edges
//     per j-iter) but wave count halves and one epilogue+prologue serves two
//     nodes (epilogue was ~half the per-wave instruction budget).
//     Safety: when one half's edges are exhausted (bn<=0) the clamped batch
//     load would hit an UNWRITTEN (poisoned) binned slot -> value sanitized
//     to 0 before it becomes a zp address.
// ---------------------------------------------------------------------------
__global__ __launch_bounds__(256) void agg_kernel(const int* __restrict__ meta,
                                                  const int* __restrict__ binned,
                                                  const __half* __restrict__ zp,
                                                  const float* __restrict__ b,
                                                  float* __restrict__ out) {
    const int wid  = threadIdx.x >> 6;          // 0..3
    const int lane = threadIdx.x & 63;
    const int half = lane >> 5;                 // 0 = node A, 1 = node B
    const int l31  = lane & 31;
    const int sub  = (lane >> 3) & 3;           // edge slot 0..3 within node
    const int o8   = (lane & 7) * 8;            // class octet start

    const int nodeA = blockIdx.x * 8 + wid * 2;
    const int node  = nodeA + half;

    const unsigned mvA = (unsigned)meta[nodeA];
    const unsigned mvB = (unsigned)meta[nodeA + 1];
    const int cA = mvA >> 21;
    const int cB = mvB >> 21;
    const int st  = half ? (int)(mvB & 0x1FFFFF) : (int)(mvA & 0x1FFFFF);
    const int cnt = half ? cB : cA;
    const int cmax = max(cA, cB);

    float a[8] = {0.f, 0.f, 0.f, 0.f, 0.f, 0.f, 0.f, 0.f};
    for (int base = 0; base < cmax; base += 32) {
        const int bn = cnt - base;              // may be <=0 for this half
        const int idxoff = max(min(l31, bn - 1), 0);
        int sv = binned[st + base + idxoff];
        if (bn <= 0) sv = 0;                    // sanitize poison (never deref)
        const int jn = min(cmax - base, 32);
        const int jm = (jn + 3) >> 2;
        for (int j = 0; j < jm; j++) {
            const int eid = j * 4 + sub;
            const int srcl = (half << 5) + max(min(eid, bn - 1), 0);
            const int row = __shfl(sv, srcl, 64);
            const u32x4 g = *(const u32x4*)&zp[row * N_CLASSES + o8];
            if (eid < bn) {
#pragma unroll
                for (int k = 0; k < 4; k++) {
                    float2 f = h2f2(g[k]);
                    a[2 * k]     += f.x;
                    a[2 * k + 1] += f.y;
                }
            }
        }
    }
    // combine the 4 edge slots (xor 8,16 — stays within each 32-lane half)
#pragma unroll
    for (int mask = 8; mask <= 16; mask <<= 1)
#pragma unroll
        for (int k = 0; k < 8; k++)
            a[k] += __shfl_xor(a[k], mask, 64);

    // self-loop
    const u32x4 sg = *(const u32x4*)&zp[node * N_CLASSES + o8];
#pragma unroll
    for (int k = 0; k < 4; k++) {
        float2 f = h2f2(sg[k]);
        a[2 * k]     += f.x;
        a[2 * k + 1] += f.y;
    }

    const float dinv = rsqrtf((float)(cnt + 1));
    float v[8];
#pragma unroll
    for (int k = 0; k < 8; k++) v[k] = a[k] * dinv + b[o8 + k];

    // max/sum over 8 local + the 8 octet lanes (masks 1,2,4 stay in-octet,
    // combining the 8 octets within this node's sub-group)
    float m = v[0];
#pragma unroll
    for (int k = 1; k < 8; k++) m = fmaxf(m, v[k]);
#pragma unroll
    for (int mask = 1; mask <= 4; mask <<= 1)
        m = fmaxf(m, __shfl_xor(m, mask, 64));
    float l = 0.f;
#pragma unroll
    for (int k = 0; k < 8; k++) l += __expf(v[k] - m);
#pragma unroll
    for (int mask = 1; mask <= 4; mask <<= 1)
        l += __shfl_xor(l, mask, 64);
    const float lg = m + __logf(l);

    if (sub == 0) {
        float4 o0, o1;
        o0.x = v[0] - lg; o0.y = v[1] - lg; o0.z = v[2] - lg; o0.w = v[3] - lg;
        o1.x = v[4] - lg; o1.y = v[5] - lg; o1.z = v[6] - lg; o1.w = v[7] - lg;
        *(float4*)&out[node * N_CLASSES + o8]     = o0;
        *(float4*)&out[node * N_CLASSES + o8 + 4] = o1;
    }
}

// ---------------------------------------------------------------------------
// Launch
// ---------------------------------------------------------------------------
extern "C" void kernel_launch(void* const* d_in, const int* in_sizes, int n_in,
                              void* d_out, int out_size, void* d_ws, size_t ws_size,
                              hipStream_t stream) {
    const float* x    = (const float*)d_in[0];
    const int*   edge = (const int*)d_in[1];   // [2,E]: src then dst
    const float* W    = (const float*)d_in[2];
    const float* b    = (const float*)d_in[3];
    float* out = (float*)d_out;

    char* ws = (char*)d_ws;
    int*    meta   = (int*)(ws);
    int*    bcnt   = (int*)(ws + OFF_BCNT);
    int*    binned = (int*)(ws + OFF_BINNED);
    __half* zp     = (__half*)(ws + OFF_ZP);

    const int* srcv = edge;
    const int* dstv = edge + N_EDGES;

    hipMemsetAsync(bcnt, 0, NB * sizeof(int), stream);
    bin_kernel<<<NBLK_A, 1024, 0, stream>>>(srcv, dstv, bcnt, binned);
    sortdeg_kernel<<<NB, 1024, 0, stream>>>(bcnt, binned, meta);
    gemm_kernel<<<NBLK_G, 256, 0, stream>>>(x, W, meta, zp);
    agg_kernel<<<N_NODES / 8, 256, 0, stream>>>(meta, binned, zp, b, out);
}

// Round 6
// 175.029 us; speedup vs baseline: 1.1442x; 1.0142x over previous
//
#include <hip/hip_runtime.h>
#include <hip/hip_bf16.h>
#include <hip/hip_fp16.h>
#include <math.h>

#define N_NODES   100000
#define N_EDGES   1600000
#define D_FEAT    128
#define N_CLASSES 64

#define BKT_SHIFT 7                     // 128 nodes per bucket
#define BKT_NODES 128
#define NB        782                   // ceil(100000/128)
#define CAP       2560                  // per-bucket capacity (avg 2048)
#define CHUNK     8192                  // edges per bin block
#define NBLK_A    ((N_EDGES + CHUNK - 1) / CHUNK)   // 196
#define NBLK_G    ((N_NODES + 63) / 64)             // 1563

// ws layout (max extent 21,212,160 B):
//   meta   @ 0          (400,000 B)  start|(indeg<<21)
//   bcnt   @ 400,384    (3,128 B)
//   binned @ 404,480    (8,007,680 B)
//   zp     @ 8,412,160  (12,800,000 B, fp16)
#define OFF_BCNT   400384
#define OFF_BINNED 404480
#define OFF_ZP     8412160

typedef __attribute__((ext_vector_type(8))) short bf16x8;
typedef __attribute__((ext_vector_type(4))) float f32x4;
typedef __attribute__((ext_vector_type(4))) unsigned int u32x4;

static __device__ inline unsigned f2bf1(float f) {
    unsigned u = __float_as_uint(f);
    return (u + 0x7FFF + ((u >> 16) & 1)) >> 16;     // RNE
}
static __device__ inline unsigned pack2(float a, float b) {
    return f2bf1(a) | (f2bf1(b) << 16);
}
static __device__ inline float2 h2f2(unsigned u) {
    __half2 h = *(__half2*)&u;
    return __half22float2(h);
}

// ---------------------------------------------------------------------------
// K1: bin edges into NB coarse buckets. v2: bucket-sort the chunk in LDS and
//     write each bucket's run COALESCED. The old version's 4B stores hit
//     ~8192 distinct cachelines per block spread over 8 MB -> partially-
//     dirty-line RMW at HBM (theory: the hidden ~40 us). Now ~1-2 lines/run.
// ---------------------------------------------------------------------------
__global__ __launch_bounds__(1024) void bin_kernel(const int* __restrict__ src,
                                                   const int* __restrict__ dst,
                                                   int* __restrict__ bcnt,
                                                   int* __restrict__ binned) {
    __shared__ int hist[NB];                   // counts, then scatter cursor
    __shared__ int rbase[NB];                  // global run base (via bcnt)
    __shared__ int loc[NB];                    // exclusive prefix within block
    __shared__ int wsum[16];
    __shared__ int dbuf[CHUNK];                // staged dst (32 KB)
    __shared__ int sbuf[CHUNK];                // bucket-sorted packed (32 KB)

    const int tid  = threadIdx.x;
    const int lane = tid & 63;
    const int wid  = tid >> 6;
    const int e0 = blockIdx.x * CHUNK;
    const int e1 = min(e0 + CHUNK, N_EDGES);
    const int n  = e1 - e0;

    if (tid < NB) hist[tid] = 0;
    __syncthreads();

    // pass 1: stage dst + histogram
    for (int i = tid; i < n; i += 1024) {
        int d = dst[e0 + i];
        dbuf[i] = d;
        atomicAdd(&hist[d >> BKT_SHIFT], 1);
    }
    __syncthreads();

    // pass 2: block-wide exclusive scan of hist -> loc; reserve global runs
    int x = (tid < NB) ? hist[tid] : 0;
    int sc = x;
#pragma unroll
    for (int off = 1; off < 64; off <<= 1) {
        int t = __shfl_up(sc, off, 64);
        if (lane >= off) sc += t;
    }
    if (lane == 63) wsum[wid] = sc;
    __syncthreads();
    if (tid < 16) {
        int w  = wsum[tid];
        int ws = w;
#pragma unroll
        for (int off = 1; off < 16; off <<= 1) {
            int t = __shfl_up(ws, off, 16);
            if (tid >= off) ws += t;
        }
        wsum[tid] = ws - w;                    // exclusive wave offset
    }
    __syncthreads();
    if (tid < NB) {
        loc[tid] = sc - x + wsum[wid];         // exclusive prefix
        if (x) rbase[tid] = atomicAdd(&bcnt[tid], x);
        hist[tid] = 0;                         // reuse as scatter cursor
    }
    __syncthreads();

    // pass 3: scatter into bucket-sorted LDS order
    for (int i = tid; i < n; i += 1024) {
        int d   = dbuf[i];
        int sv  = src[e0 + i];
        int bkt = d >> BKT_SHIFT;
        int p   = atomicAdd(&hist[bkt], 1);    // hist returns to count after
        sbuf[loc[bkt] + p] = (sv << BKT_SHIFT) | (d & (BKT_NODES - 1));
    }
    __syncthreads();

    // pass 4: write runs out coalesced (16-lane group per bucket run)
    const int g16 = lane >> 4;                 // 0..3
    const int l16 = lane & 15;
    for (int b2 = wid * 4 + g16; b2 < NB; b2 += 64) {
        const int len = hist[b2];
        if (!len) continue;
        const int st = loc[b2];
        const int rb = rbase[b2];
        for (int k = l16; k < len; k += 16) {
            const int off = rb + k;
            if (off < CAP)                     // memory guard
                binned[b2 * CAP + off] = sbuf[st + k];
        }
    }
}

// ---------------------------------------------------------------------------
// K2: per-bucket in-place sort-by-node + degree metadata. (round-0 form)
// ---------------------------------------------------------------------------
__global__ __launch_bounds__(1024) void sortdeg_kernel(const int* __restrict__ bcnt,
                                                       int* __restrict__ binned,
                                                       int* __restrict__ meta) {
    __shared__ int buf[CAP];
    __shared__ int hcnt[BKT_NODES];
    __shared__ int cur[BKT_NODES];
    __shared__ int rowstart[BKT_NODES + 1];

    const int tid  = threadIdx.x;
    const int lane = tid & 63;
    const int wid  = tid >> 6;

    if (tid < BKT_NODES) { hcnt[tid] = 0; cur[tid] = 0; }
    __syncthreads();

    const int n    = min(bcnt[blockIdx.x], CAP);
    const int base = blockIdx.x * CAP;

    for (int i = tid; i < n; i += 1024) {
        int v = binned[base + i];
        buf[i] = v;
        atomicAdd(&hcnt[v & (BKT_NODES - 1)], 1);
    }
    __syncthreads();

    if (wid == 0) {
        int v0 = hcnt[lane];
        int v1 = hcnt[64 + lane];
        int s0 = v0;
#pragma unroll
        for (int off = 1; off < 64; off <<= 1) {
            int t = __shfl_up(s0, off, 64);
            if (lane >= off) s0 += t;
        }
        int tot0 = __shfl(s0, 63, 64);
        int s1 = v1;
#pragma unroll
        for (int off = 1; off < 64; off <<= 1) {
            int t = __shfl_up(s1, off, 64);
            if (lane >= off) s1 += t;
        }
        s1 += tot0;
        if (lane == 0) rowstart[0] = 0;
        rowstart[1 + lane]  = s0;
        rowstart[65 + lane] = s1;
    }
    __syncthreads();

    for (int i = tid; i < n; i += 1024) {
        int v  = buf[i];
        int nd = v & (BKT_NODES - 1);
        int p  = atomicAdd(&cur[nd], 1);
        binned[base + rowstart[nd] + p] = v >> BKT_SHIFT;
    }

    if (tid < BKT_NODES) {
        int node = blockIdx.x * BKT_NODES + tid;
        if (node < N_NODES) {
            int st = base + rowstart[tid];
            int dg = min(hcnt[tid], 2047);
            meta[node] = st | (dg << 21);
        }
    }
}

// ---------------------------------------------------------------------------
// K3: zp[i][c] = rsqrt(indeg[i]+1) * (x @ W^T)[i][c]  via bf16 MFMA, fp16 out.
// ---------------------------------------------------------------------------
__global__ __launch_bounds__(256) void gemm_kernel(const float* __restrict__ x,
                                                   const float* __restrict__ W,
                                                   const int* __restrict__ meta,
                                                   __half* __restrict__ zp) {
    __shared__ short Xb[64 * 136];
    __shared__ short Wb[64 * 136];
    const int tid  = threadIdx.x;
    const int row0 = blockIdx.x * 64;

    const float4* __restrict__ W4 = (const float4*)W;
    for (int idx = tid; idx < 64 * 32; idx += 256) {
        int nn = idx >> 5, k4 = idx & 31;
        float4 v = W4[idx];
        uint2 p;
        p.x = pack2(v.x, v.y);
        p.y = pack2(v.z, v.w);
        *(uint2*)&Wb[nn * 136 + k4 * 4] = p;
    }
    const float4* __restrict__ x4 = (const float4*)x;
    for (int idx = tid; idx < 64 * 32; idx += 256) {
        int r = idx >> 5, k4 = idx & 31;
        int gr = min(row0 + r, N_NODES - 1);
        float4 v = x4[gr * 32 + k4];
        uint2 p;
        p.x = pack2(v.x, v.y);
        p.y = pack2(v.z, v.w);
        *(uint2*)&Xb[r * 136 + k4 * 4] = p;
    }
    __syncthreads();

    const int lane = tid & 63;
    const int wv   = tid >> 6;
    const int m    = lane & 15;
    const int half = lane >> 4;

    bf16x8 bfr[4][4];
#pragma unroll
    for (int t = 0; t < 4; t++)
#pragma unroll
        for (int j = 0; j < 4; j++)
            bfr[t][j] = *(bf16x8*)&Wb[(j * 16 + m) * 136 + t * 32 + half * 8];

    f32x4 acc[4];
#pragma unroll
    for (int j = 0; j < 4; j++) acc[j] = (f32x4){0.f, 0.f, 0.f, 0.f};

#pragma unroll
    for (int t = 0; t < 4; t++) {
        bf16x8 a = *(bf16x8*)&Xb[(wv * 16 + m) * 136 + t * 32 + half * 8];
#pragma unroll
        for (int j = 0; j < 4; j++)
            acc[j] = __builtin_amdgcn_mfma_f32_16x16x32_bf16(a, bfr[t][j], acc[j], 0, 0, 0);
    }

#pragma unroll
    for (int r = 0; r < 4; r++) {
        const int row = row0 + wv * 16 + half * 4 + r;
        if (row < N_NODES) {
            const int dg = ((unsigned)meta[row]) >> 21;
            const float dinv = rsqrtf((float)(dg + 1));
#pragma unroll
            for (int j = 0; j < 4; j++)
                zp[row * N_CLASSES + j * 16 + m] = __float2half(acc[j][r] * dinv);
        }
    }
}

// ---------------------------------------------------------------------------
// K4: gather-accumulate + fused epilogue. TWO nodes per wave (round-5 proven).
// ---------------------------------------------------------------------------
__global__ __launch_bounds__(256) void agg_kernel(const int* __restrict__ meta,
                                                  const int* __restrict__ binned,
                                                  const __half* __restrict__ zp,
                                                  const float* __restrict__ b,
                                                  float* __restrict__ out) {
    const int wid  = threadIdx.x >> 6;          // 0..3
    const int lane = threadIdx.x & 63;
    const int half = lane >> 5;                 // 0 = node A, 1 = node B
    const int l31  = lane & 31;
    const int sub  = (lane >> 3) & 3;           // edge slot 0..3 within node
    const int o8   = (lane & 7) * 8;            // class octet start

    const int nodeA = blockIdx.x * 8 + wid * 2;
    const int node  = nodeA + half;

    const unsigned mvA = (unsigned)meta[nodeA];
    const unsigned mvB = (unsigned)meta[nodeA + 1];
    const int cA = mvA >> 21;
    const int cB = mvB >> 21;
    const int st  = half ? (int)(mvB & 0x1FFFFF) : (int)(mvA & 0x1FFFFF);
    const int cnt = half ? cB : cA;
    const int cmax = max(cA, cB);

    float a[8] = {0.f, 0.f, 0.f, 0.f, 0.f, 0.f, 0.f, 0.f};
    for (int base = 0; base < cmax; base += 32) {
        const int bn = cnt - base;              // may be <=0 for this half
        const int idxoff = max(min(l31, bn - 1), 0);
        int sv = binned[st + base + idxoff];
        if (bn <= 0) sv = 0;                    // sanitize poison (never deref)
        const int jn = min(cmax - base, 32);
        const int jm = (jn + 3) >> 2;
        for (int j = 0; j < jm; j++) {
            const int eid = j * 4 + sub;
            const int srcl = (half << 5) + max(min(eid, bn - 1), 0);
            const int row = __shfl(sv, srcl, 64);
            const u32x4 g = *(const u32x4*)&zp[row * N_CLASSES + o8];
            if (eid < bn) {
#pragma unroll
                for (int k = 0; k < 4; k++) {
                    float2 f = h2f2(g[k]);
                    a[2 * k]     += f.x;
                    a[2 * k + 1] += f.y;
                }
            }
        }
    }
    // combine the 4 edge slots (xor 8,16 — stays within each 32-lane half)
#pragma unroll
    for (int mask = 8; mask <= 16; mask <<= 1)
#pragma unroll
        for (int k = 0; k < 8; k++)
            a[k] += __shfl_xor(a[k], mask, 64);

    // self-loop
    const u32x4 sg = *(const u32x4*)&zp[node * N_CLASSES + o8];
#pragma unroll
    for (int k = 0; k < 4; k++) {
        float2 f = h2f2(sg[k]);
        a[2 * k]     += f.x;
        a[2 * k + 1] += f.y;
    }

    const float dinv = rsqrtf((float)(cnt + 1));
    float v[8];
#pragma unroll
    for (int k = 0; k < 8; k++) v[k] = a[k] * dinv + b[o8 + k];

    float m = v[0];
#pragma unroll
    for (int k = 1; k < 8; k++) m = fmaxf(m, v[k]);
#pragma unroll
    for (int mask = 1; mask <= 4; mask <<= 1)
        m = fmaxf(m, __shfl_xor(m, mask, 64));
    float l = 0.f;
#pragma unroll
    for (int k = 0; k < 8; k++) l += __expf(v[k] - m);
#pragma unroll
    for (int mask = 1; mask <= 4; mask <<= 1)
        l += __shfl_xor(l, mask, 64);
    const float lg = m + __logf(l);

    if (sub == 0) {
        float4 o0, o1;
        o0.x = v[0] - lg; o0.y = v[1] - lg; o0.z = v[2] - lg; o0.w = v[3] - lg;
        o1.x = v[4] - lg; o1.y = v[5] - lg; o1.z = v[6] - lg; o1.w = v[7] - lg;
        *(float4*)&out[node * N_CLASSES + o8]     = o0;
        *(float4*)&out[node * N_CLASSES + o8 + 4] = o1;
    }
}

// ---------------------------------------------------------------------------
// Launch
// ---------------------------------------------------------------------------
extern "C" void kernel_launch(void* const* d_in, const int* in_sizes, int n_in,
                              void* d_out, int out_size, void* d_ws, size_t ws_size,
                              hipStream_t stream) {
    const float* x    = (const float*)d_in[0];
    const int*   edge = (const int*)d_in[1];   // [2,E]: src then dst
    const float* W    = (const float*)d_in[2];
    const float* b    = (const float*)d_in[3];
    float* out = (float*)d_out;

    char* ws = (char*)d_ws;
    int*    meta   = (int*)(ws);
    int*    bcnt   = (int*)(ws + OFF_BCNT);
    int*    binned = (int*)(ws + OFF_BINNED);
    __half* zp     = (__half*)(ws + OFF_ZP);

    const int* srcv = edge;
    const int* dstv = edge + N_EDGES;

    hipMemsetAsync(bcnt, 0, NB * sizeof(int), stream);
    bin_kernel<<<NBLK_A, 1024, 0, stream>>>(srcv, dstv, bcnt, binned);
    sortdeg_kernel<<<NB, 1024, 0, stream>>>(bcnt, binned, meta);
    gemm_kernel<<<NBLK_G, 256, 0, stream>>>(x, W, meta, zp);
    agg_kernel<<<N_NODES / 8, 256, 0, stream>>>(meta, binned, zp, b, out);
}

// Round 7
// 169.164 us; speedup vs baseline: 1.1839x; 1.0347x over previous
//
#include <hip/hip_runtime.h>
#include <hip/hip_bf16.h>
#include <hip/hip_fp16.h>
#include <math.h>

#define N_NODES   100000
#define N_EDGES   1600000
#define D_FEAT    128
#define N_CLASSES 64

#define BKT_SHIFT 7                     // 128 nodes per bucket
#define BKT_NODES 128
#define NB        782                   // ceil(100000/128)
#define CAP       2560                  // per-bucket capacity (avg 2048)
#define CHUNK     8192                  // edges per bin block
#define NBLK_A    ((N_EDGES + CHUNK - 1) / CHUNK)   // 196
#define GROWS     128                   // rows per gemm block (2 tiles of 64)
#define NBLK_G    ((N_NODES + GROWS - 1) / GROWS)   // 782

// ws layout (max extent 21,212,160 B):
//   meta   @ 0          (400,000 B)  start|(indeg<<21)
//   bcnt   @ 400,384    (3,128 B)
//   binned @ 404,480    (8,007,680 B)
//   zp     @ 8,412,160  (12,800,000 B, fp16)
#define OFF_BCNT   400384
#define OFF_BINNED 404480
#define OFF_ZP     8412160

typedef __attribute__((ext_vector_type(8))) short bf16x8;
typedef __attribute__((ext_vector_type(4))) float f32x4;
typedef __attribute__((ext_vector_type(4))) unsigned int u32x4;

static __device__ inline unsigned f2bf1(float f) {
    unsigned u = __float_as_uint(f);
    return (u + 0x7FFF + ((u >> 16) & 1)) >> 16;     // RNE
}
static __device__ inline unsigned pack2(float a, float b) {
    return f2bf1(a) | (f2bf1(b) << 16);
}
static __device__ inline float2 h2f2(unsigned u) {
    __half2 h = *(__half2*)&u;
    return __half22float2(h);
}

// ---------------------------------------------------------------------------
// K1: bin edges into NB coarse buckets; LDS bucket-sort, coalesced run writes.
//     (round-6 form, proven)
// ---------------------------------------------------------------------------
__global__ __launch_bounds__(1024) void bin_kernel(const int* __restrict__ src,
                                                   const int* __restrict__ dst,
                                                   int* __restrict__ bcnt,
                                                   int* __restrict__ binned) {
    __shared__ int hist[NB];                   // counts, then scatter cursor
    __shared__ int rbase[NB];                  // global run base (via bcnt)
    __shared__ int loc[NB];                    // exclusive prefix within block
    __shared__ int wsum[16];
    __shared__ int dbuf[CHUNK];                // staged dst (32 KB)
    __shared__ int sbuf[CHUNK];                // bucket-sorted packed (32 KB)

    const int tid  = threadIdx.x;
    const int lane = tid & 63;
    const int wid  = tid >> 6;
    const int e0 = blockIdx.x * CHUNK;
    const int e1 = min(e0 + CHUNK, N_EDGES);
    const int n  = e1 - e0;

    if (tid < NB) hist[tid] = 0;
    __syncthreads();

    // pass 1: stage dst + histogram
    for (int i = tid; i < n; i += 1024) {
        int d = dst[e0 + i];
        dbuf[i] = d;
        atomicAdd(&hist[d >> BKT_SHIFT], 1);
    }
    __syncthreads();

    // pass 2: block-wide exclusive scan of hist -> loc; reserve global runs
    int x = (tid < NB) ? hist[tid] : 0;
    int sc = x;
#pragma unroll
    for (int off = 1; off < 64; off <<= 1) {
        int t = __shfl_up(sc, off, 64);
        if (lane >= off) sc += t;
    }
    if (lane == 63) wsum[wid] = sc;
    __syncthreads();
    if (tid < 16) {
        int w  = wsum[tid];
        int ws = w;
#pragma unroll
        for (int off = 1; off < 16; off <<= 1) {
            int t = __shfl_up(ws, off, 16);
            if (tid >= off) ws += t;
        }
        wsum[tid] = ws - w;                    // exclusive wave offset
    }
    __syncthreads();
    if (tid < NB) {
        loc[tid] = sc - x + wsum[wid];         // exclusive prefix
        if (x) rbase[tid] = atomicAdd(&bcnt[tid], x);
        hist[tid] = 0;                         // reuse as scatter cursor
    }
    __syncthreads();

    // pass 3: scatter into bucket-sorted LDS order
    for (int i = tid; i < n; i += 1024) {
        int d   = dbuf[i];
        int sv  = src[e0 + i];
        int bkt = d >> BKT_SHIFT;
        int p   = atomicAdd(&hist[bkt], 1);
        sbuf[loc[bkt] + p] = (sv << BKT_SHIFT) | (d & (BKT_NODES - 1));
    }
    __syncthreads();

    // pass 4: write runs out coalesced (16-lane group per bucket run)
    const int g16 = lane >> 4;                 // 0..3
    const int l16 = lane & 15;
    for (int b2 = wid * 4 + g16; b2 < NB; b2 += 64) {
        const int len = hist[b2];
        if (!len) continue;
        const int st = loc[b2];
        const int rb = rbase[b2];
        for (int k = l16; k < len; k += 16) {
            const int off = rb + k;
            if (off < CAP)                     // memory guard
                binned[b2 * CAP + off] = sbuf[st + k];
        }
    }
}

// ---------------------------------------------------------------------------
// K2: per-bucket in-place sort-by-node + degree metadata. (round-0 form)
// ---------------------------------------------------------------------------
__global__ __launch_bounds__(1024) void sortdeg_kernel(const int* __restrict__ bcnt,
                                                       int* __restrict__ binned,
                                                       int* __restrict__ meta) {
    __shared__ int buf[CAP];
    __shared__ int hcnt[BKT_NODES];
    __shared__ int cur[BKT_NODES];
    __shared__ int rowstart[BKT_NODES + 1];

    const int tid  = threadIdx.x;
    const int lane = tid & 63;
    const int wid  = tid >> 6;

    if (tid < BKT_NODES) { hcnt[tid] = 0; cur[tid] = 0; }
    __syncthreads();

    const int n    = min(bcnt[blockIdx.x], CAP);
    const int base = blockIdx.x * CAP;

    for (int i = tid; i < n; i += 1024) {
        int v = binned[base + i];
        buf[i] = v;
        atomicAdd(&hcnt[v & (BKT_NODES - 1)], 1);
    }
    __syncthreads();

    if (wid == 0) {
        int v0 = hcnt[lane];
        int v1 = hcnt[64 + lane];
        int s0 = v0;
#pragma unroll
        for (int off = 1; off < 64; off <<= 1) {
            int t = __shfl_up(s0, off, 64);
            if (lane >= off) s0 += t;
        }
        int tot0 = __shfl(s0, 63, 64);
        int s1 = v1;
#pragma unroll
        for (int off = 1; off < 64; off <<= 1) {
            int t = __shfl_up(s1, off, 64);
            if (lane >= off) s1 += t;
        }
        s1 += tot0;
        if (lane == 0) rowstart[0] = 0;
        rowstart[1 + lane]  = s0;
        rowstart[65 + lane] = s1;
    }
    __syncthreads();

    for (int i = tid; i < n; i += 1024) {
        int v  = buf[i];
        int nd = v & (BKT_NODES - 1);
        int p  = atomicAdd(&cur[nd], 1);
        binned[base + rowstart[nd] + p] = v >> BKT_SHIFT;
    }

    if (tid < BKT_NODES) {
        int node = blockIdx.x * BKT_NODES + tid;
        if (node < N_NODES) {
            int st = base + rowstart[tid];
            int dg = min(hcnt[tid], 2047);
            meta[node] = st | (dg << 21);
        }
    }
}

// ---------------------------------------------------------------------------
// K3 v3: zp[i][c] = rsqrt(indeg[i]+1) * (x @ W^T)[i][c]  via bf16 MFMA.
//     A-frags loaded DIRECTLY from global (2 aligned float4 per lane per t;
//     half-pairs consume full 64B lines -> ideal traffic), converted to bf16
//     in-register. No X LDS round-trip, no per-tile syncs. W staged to LDS
//     once per block, frags hoisted to 64 VGPRs, amortized over 2 row-tiles.
// ---------------------------------------------------------------------------
__global__ __launch_bounds__(256) void gemm_kernel(const float* __restrict__ x,
                                                   const float* __restrict__ W,
                                                   const int* __restrict__ meta,
                                                   __half* __restrict__ zp) {
    __shared__ short Wb[64 * 136];
    const int tid  = threadIdx.x;

    const float4* __restrict__ W4 = (const float4*)W;
    for (int idx = tid; idx < 64 * 32; idx += 256) {
        int nn = idx >> 5, k4 = idx & 31;
        float4 v = W4[idx];
        uint2 p;
        p.x = pack2(v.x, v.y);
        p.y = pack2(v.z, v.w);
        *(uint2*)&Wb[nn * 136 + k4 * 4] = p;
    }
    __syncthreads();

    const int lane = tid & 63;
    const int wv   = tid >> 6;
    const int m    = lane & 15;
    const int half = lane >> 4;

    bf16x8 bfr[4][4];
#pragma unroll
    for (int t = 0; t < 4; t++)
#pragma unroll
        for (int j = 0; j < 4; j++)
            bfr[t][j] = *(bf16x8*)&Wb[(j * 16 + m) * 136 + t * 32 + half * 8];

#pragma unroll
    for (int rt = 0; rt < 2; rt++) {
        const int row0 = blockIdx.x * GROWS + rt * 64;
        const int arow = min(row0 + wv * 16 + m, N_NODES - 1);
        const float4* __restrict__ xr = (const float4*)&x[arow * D_FEAT];

        f32x4 acc[4];
#pragma unroll
        for (int j = 0; j < 4; j++) acc[j] = (f32x4){0.f, 0.f, 0.f, 0.f};

#pragma unroll
        for (int t = 0; t < 4; t++) {
            const float4 p0 = xr[t * 8 + half * 2];
            const float4 p1 = xr[t * 8 + half * 2 + 1];
            union { bf16x8 v; unsigned u[4]; } au;
            au.u[0] = pack2(p0.x, p0.y);
            au.u[1] = pack2(p0.z, p0.w);
            au.u[2] = pack2(p1.x, p1.y);
            au.u[3] = pack2(p1.z, p1.w);
#pragma unroll
            for (int j = 0; j < 4; j++)
                acc[j] = __builtin_amdgcn_mfma_f32_16x16x32_bf16(au.v, bfr[t][j], acc[j], 0, 0, 0);
        }

#pragma unroll
        for (int r = 0; r < 4; r++) {
            const int row = row0 + wv * 16 + half * 4 + r;
            if (row < N_NODES) {
                const int dg = ((unsigned)meta[row]) >> 21;
                const float dinv = rsqrtf((float)(dg + 1));
#pragma unroll
                for (int j = 0; j < 4; j++)
                    zp[row * N_CLASSES + j * 16 + m] = __float2half(acc[j][r] * dinv);
            }
        }
    }
}

// ---------------------------------------------------------------------------
// K4: gather-accumulate + fused epilogue. TWO nodes per wave (round-5 proven).
// ---------------------------------------------------------------------------
__global__ __launch_bounds__(256) void agg_kernel(const int* __restrict__ meta,
                                                  const int* __restrict__ binned,
                                                  const __half* __restrict__ zp,
                                                  const float* __restrict__ b,
                                                  float* __restrict__ out) {
    const int wid  = threadIdx.x >> 6;          // 0..3
    const int lane = threadIdx.x & 63;
    const int half = lane >> 5;                 // 0 = node A, 1 = node B
    const int l31  = lane & 31;
    const int sub  = (lane >> 3) & 3;           // edge slot 0..3 within node
    const int o8   = (lane & 7) * 8;            // class octet start

    const int nodeA = blockIdx.x * 8 + wid * 2;
    const int node  = nodeA + half;

    const unsigned mvA = (unsigned)meta[nodeA];
    const unsigned mvB = (unsigned)meta[nodeA + 1];
    const int cA = mvA >> 21;
    const int cB = mvB >> 21;
    const int st  = half ? (int)(mvB & 0x1FFFFF) : (int)(mvA & 0x1FFFFF);
    const int cnt = half ? cB : cA;
    const int cmax = max(cA, cB);

    float a[8] = {0.f, 0.f, 0.f, 0.f, 0.f, 0.f, 0.f, 0.f};
    for (int base = 0; base < cmax; base += 32) {
        const int bn = cnt - base;              // may be <=0 for this half
        const int idxoff = max(min(l31, bn - 1), 0);
        int sv = binned[st + base + idxoff];
        if (bn <= 0) sv = 0;                    // sanitize poison (never deref)
        const int jn = min(cmax - base, 32);
        const int jm = (jn + 3) >> 2;
        for (int j = 0; j < jm; j++) {
            const int eid = j * 4 + sub;
            const int srcl = (half << 5) + max(min(eid, bn - 1), 0);
            const int row = __shfl(sv, srcl, 64);
            const u32x4 g = *(const u32x4*)&zp[row * N_CLASSES + o8];
            if (eid < bn) {
#pragma unroll
                for (int k = 0; k < 4; k++) {
                    float2 f = h2f2(g[k]);
                    a[2 * k]     += f.x;
                    a[2 * k + 1] += f.y;
                }
            }
        }
    }
    // combine the 4 edge slots (xor 8,16 — stays within each 32-lane half)
#pragma unroll
    for (int mask = 8; mask <= 16; mask <<= 1)
#pragma unroll
        for (int k = 0; k < 8; k++)
            a[k] += __shfl_xor(a[k], mask, 64);

    // self-loop
    const u32x4 sg = *(const u32x4*)&zp[node * N_CLASSES + o8];
#pragma unroll
    for (int k = 0; k < 4; k++) {
        float2 f = h2f2(sg[k]);
        a[2 * k]     += f.x;
        a[2 * k + 1] += f.y;
    }

    const float dinv = rsqrtf((float)(cnt + 1));
    float v[8];
#pragma unroll
    for (int k = 0; k < 8; k++) v[k] = a[k] * dinv + b[o8 + k];

    float m = v[0];
#pragma unroll
    for (int k = 1; k < 8; k++) m = fmaxf(m, v[k]);
#pragma unroll
    for (int mask = 1; mask <= 4; mask <<= 1)
        m = fmaxf(m, __shfl_xor(m, mask, 64));
    float l = 0.f;
#pragma unroll
    for (int k = 0; k < 8; k++) l += __expf(v[k] - m);
#pragma unroll
    for (int mask = 1; mask <= 4; mask <<= 1)
        l += __shfl_xor(l, mask, 64);
    const float lg = m + __logf(l);

    if (sub == 0) {
        float4 o0, o1;
        o0.x = v[0] - lg; o0.y = v[1] - lg; o0.z = v[2] - lg; o0.w = v[3] - lg;
        o1.x = v[4] - lg; o1.y = v[5] - lg; o1.z = v[6] - lg; o1.w = v[7] - lg;
        *(float4*)&out[node * N_CLASSES + o8]     = o0;
        *(float4*)&out[node * N_CLASSES + o8 + 4] = o1;
    }
}

// ---------------------------------------------------------------------------
// Launch
// ---------------------------------------------------------------------------
extern "C" void kernel_launch(void* const* d_in, const int* in_sizes, int n_in,
                              void* d_out, int out_size, void* d_ws, size_t ws_size,
                              hipStream_t stream) {
    const float* x    = (const float*)d_in[0];
    const int*   edge = (const int*)d_in[1];   // [2,E]: src then dst
    const float* W    = (const float*)d_in[2];
    const float* b    = (const float*)d_in[3];
    float* out = (float*)d_out;

    char* ws = (char*)d_ws;
    int*    meta   = (int*)(ws);
    int*    bcnt   = (int*)(ws + OFF_BCNT);
    int*    binned = (int*)(ws + OFF_BINNED);
    __half* zp     = (__half*)(ws + OFF_ZP);

    const int* srcv = edge;
    const int* dstv = edge + N_EDGES;

    hipMemsetAsync(bcnt, 0, NB * sizeof(int), stream);
    bin_kernel<<<NBLK_A, 1024, 0, stream>>>(srcv, dstv, bcnt, binned);
    sortdeg_kernel<<<NB, 1024, 0, stream>>>(bcnt, binned, meta);
    gemm_kernel<<<NBLK_G, 256, 0, stream>>>(x, W, meta, zp);
    agg_kernel<<<N_NODES / 8, 256, 0, stream>>>(meta, binned, zp, b, out);
}